// Round 7
// baseline (434.745 us; speedup 1.0000x reference)
//
#include <hip/hip_runtime.h>

typedef unsigned short u16;
typedef unsigned int   u32;
typedef __attribute__((ext_vector_type(8))) __bf16 bf16x8;
typedef __attribute__((ext_vector_type(8))) unsigned short u16x8;
typedef __attribute__((ext_vector_type(4))) float f32x4;

#define DEVINL static __device__ __forceinline__
#define MFMA16(a,b,c) __builtin_amdgcn_mfma_f32_16x16x32_bf16((a),(b),(c),0,0,0)

#define GLOAD16(g, l) __builtin_amdgcn_global_load_lds( \
    (const __attribute__((address_space(1))) void*)(g), \
    (__attribute__((address_space(3))) void*)(l), 16, 0, 0)

#define VMC(N) asm volatile("s_waitcnt vmcnt(" #N ")" ::: "memory")

constexpr float ATT_SCALE = 0.08838834764831845f;  // 128^-0.5

DEVINL u16 f2bf(float f) {
  union { float f; u32 u; } v; v.f = f;
  u32 r = v.u + 0x7fffu + ((v.u >> 16) & 1u);   // RNE, finite inputs only
  return (u16)(r >> 16);
}

// ---------------------------------------------------------------------------
// One-shot fp32 -> bf16 conversion of hs + the 4 weight matrices.
// ---------------------------------------------------------------------------
struct CvtArgs {
  const float* src[5];
  u16*         dst[5];
  int          nblk[5];
};

__global__ __launch_bounds__(256) void cvt_bf16(CvtArgs a) {
  const int z = blockIdx.y;
  if (blockIdx.x >= a.nblk[z]) return;
  const size_t i = ((size_t)blockIdx.x * 256 + threadIdx.x) * 8;
  const float* s = a.src[z] + i;
  float4 x0 = *(const float4*)(s);
  float4 x1 = *(const float4*)(s + 4);
  u16x8 r;
  r[0]=f2bf(x0.x); r[1]=f2bf(x0.y); r[2]=f2bf(x0.z); r[3]=f2bf(x0.w);
  r[4]=f2bf(x1.x); r[5]=f2bf(x1.y); r[6]=f2bf(x1.z); r[7]=f2bf(x1.w);
  *(u16x8*)(a.dst[z] + i) = r;
}

// ---------------------------------------------------------------------------
// 256x256 phased NT-GEMM, C = A[M,K] * W[N,K]^T, M=4096, K=2048, bf16 in.
// BK=64, 512 thr = 8 waves (2M x 4N), wave tile 128x64 (acc[8][4]),
// 16 MFMA/phase, 4 phases/K-tile (q-half x ks).
// LDS = 10-slot ring x 16KB (units per K-tile T: A0,A1,B0,B1 = 4T..4T+3;
// unit j lives in slot j%10). One unit staged per phase, lead 6 phases:
// unit j staged at phase j-6; slot's prior occupant j-10 is fully read
// >=1 barrier earlier for all j (checked per j mod 4) -> WAR-safe.
// Boundary vmcnt(4) (tile T<=29), vmcnt(0) only at T==30 tail.
// N-mapping: col = bn*256 + nf*64 + wn*16 + c  -> RoPE (d,d+64) = (nf,nf+1)
// in-lane; head = bn*2 + (nf>>1).
// FUSED=1: QKV over N=6144 (z=bnf>>3); z<=1 RoPE epi, z==2 V^T epi.
// FUSED=0: plain fp32 store.
// ---------------------------------------------------------------------------

#define STAGEU(SL, TI, PA) do {                                                \
    _Pragma("unroll")                                                          \
    for (int i_ = 0; i_ < 2; ++i_) {                                           \
      const u32 p_  = i_*512 + t;                                              \
      const u32 gl_ = p_ ^ ((p_ >> 3) & 7u);                                   \
      const u16* s_ = ((PA) < 2)                                               \
        ? Ag + (size_t)(bm*256 + (PA)*128 + (gl_ >> 3))*2048                   \
             + (TI)*64 + (gl_ & 7u)*8                                          \
        : Wg + (size_t)(bnl*256 + ((PA)-2)*128 + (gl_ >> 3))*2048              \
             + (TI)*64 + (gl_ & 7u)*8;                                         \
      GLOAD16(s_, &lds[(SL)*8192 + p_*8]);                                     \
    } } while (0)

#define LDAU(SL, MFG, KS) (*(const bf16x8*)&lds[((SL)*8192 +                   \
    ((((MFG)*16 + c) << 6) + (KS)*32 + qq*8)) ^ ((u32)(c & 7) << 3)])
#define LDBU(SL, NF, KS)  (*(const bf16x8*)&lds[((SL)*8192 +                   \
    (((((NF)&1)*64 + wn*16 + c) << 6) + (KS)*32 + qq*8)) ^ ((u32)(c & 7) << 3)])

DEVINL int subm10(int x) { return x >= 10 ? x - 10 : x; }

#define GPHASE(P, Q, KS, LOADB) do {                                           \
    const int sA_ = subm10(s_tile + wm);                                       \
    bf16x8 a0_ = LDAU(sA_, (Q)*4+0, KS);                                       \
    bf16x8 a1_ = LDAU(sA_, (Q)*4+1, KS);                                       \
    bf16x8 a2_ = LDAU(sA_, (Q)*4+2, KS);                                       \
    bf16x8 a3_ = LDAU(sA_, (Q)*4+3, KS);                                       \
    if (LOADB) {                                                               \
      const int sB0_ = subm10(s_tile + 2), sB1_ = subm10(s_tile + 3);          \
      b0 = LDBU(sB0_, 0, KS); b1 = LDBU(sB0_, 1, KS);                          \
      b2 = LDBU(sB1_, 2, KS); b3 = LDBU(sB1_, 3, KS);                          \
    }                                                                          \
    if (4*T + (P) <= 121)                                                      \
      STAGEU(s_stage, T + 1 + (((P)+2)>>2), ((P)+2)&3);                        \
    s_stage = (s_stage + 1 == 10) ? 0 : s_stage + 1;                           \
    if ((P) == 3) { if (T < 30) VMC(4); else if (T == 30) VMC(0); }            \
    __builtin_amdgcn_s_barrier();                                              \
    asm volatile("s_waitcnt lgkmcnt(0)" ::: "memory");                         \
    __builtin_amdgcn_sched_barrier(0);                                         \
    __builtin_amdgcn_s_setprio(1);                                             \
    acc[(Q)*4+0][0] = MFMA16(a0_, b0, acc[(Q)*4+0][0]);                        \
    acc[(Q)*4+1][0] = MFMA16(a1_, b0, acc[(Q)*4+1][0]);                        \
    acc[(Q)*4+2][0] = MFMA16(a2_, b0, acc[(Q)*4+2][0]);                        \
    acc[(Q)*4+3][0] = MFMA16(a3_, b0, acc[(Q)*4+3][0]);                        \
    acc[(Q)*4+0][1] = MFMA16(a0_, b1, acc[(Q)*4+0][1]);                        \
    acc[(Q)*4+1][1] = MFMA16(a1_, b1, acc[(Q)*4+1][1]);                        \
    acc[(Q)*4+2][1] = MFMA16(a2_, b1, acc[(Q)*4+2][1]);                        \
    acc[(Q)*4+3][1] = MFMA16(a3_, b1, acc[(Q)*4+3][1]);                        \
    acc[(Q)*4+0][2] = MFMA16(a0_, b2, acc[(Q)*4+0][2]);                        \
    acc[(Q)*4+1][2] = MFMA16(a1_, b2, acc[(Q)*4+1][2]);                        \
    acc[(Q)*4+2][2] = MFMA16(a2_, b2, acc[(Q)*4+2][2]);                        \
    acc[(Q)*4+3][2] = MFMA16(a3_, b2, acc[(Q)*4+3][2]);                        \
    acc[(Q)*4+0][3] = MFMA16(a0_, b3, acc[(Q)*4+0][3]);                        \
    acc[(Q)*4+1][3] = MFMA16(a1_, b3, acc[(Q)*4+1][3]);                        \
    acc[(Q)*4+2][3] = MFMA16(a2_, b3, acc[(Q)*4+2][3]);                        \
    acc[(Q)*4+3][3] = MFMA16(a3_, b3, acc[(Q)*4+3][3]);                        \
    __builtin_amdgcn_s_setprio(0);                                             \
    __builtin_amdgcn_s_barrier();                                              \
  } while (0)

template<int FUSED>
__global__ __launch_bounds__(512, 1)
void gemm9(const u16* __restrict__ Ag, const u16* __restrict__ W0,
           const u16* __restrict__ W1, const u16* __restrict__ W2,
           u16* __restrict__ outq, u16* __restrict__ outk,
           u16* __restrict__ outv, float* __restrict__ outf,
           const float* __restrict__ cosp, const float* __restrict__ sinp)
{
  __shared__ __attribute__((aligned(16))) u16 lds[10 * 8192];   // 160 KB

  const int t = threadIdx.x;
  const int lane = t & 63, w = t >> 6;
  const int wm = w >> 2, wn = w & 3;
  const int c = lane & 15, qq = lane >> 4;

  // XCD-bijective bn-major chunking (gridDim.x % 8 == 0)
  const int cpx = gridDim.x >> 3;
  const int bid = blockIdx.x;
  const int wg  = (bid & 7) * cpx + (bid >> 3);
  const int bm  = wg & 15;
  const int bnf = wg >> 4;
  const int z   = FUSED ? (bnf >> 3) : 3;
  const int bnl = FUSED ? (bnf & 7) : bnf;
  const u16* Wg = FUSED ? (z == 0 ? W0 : (z == 1 ? W1 : W2)) : W0;

  f32x4 acc[8][4] = {};
  bf16x8 b0, b1, b2, b3;

  // Prologue: units 0..5 (tile0 A0,A1,B0,B1 + tile1 A0,A1) into slots 0..5.
  STAGEU(0, 0, 0); STAGEU(1, 0, 1); STAGEU(2, 0, 2); STAGEU(3, 0, 3);
  STAGEU(4, 1, 0); STAGEU(5, 1, 1);
  VMC(4);                         // tile 0 landed; units 4,5 in flight
  __builtin_amdgcn_s_barrier();

  int s_tile = 0, s_stage = 6;
  #pragma unroll 1
  for (int T = 0; T < 32; ++T) {
    GPHASE(0, 0, 0, 1);
    GPHASE(1, 1, 0, 0);
    GPHASE(2, 0, 1, 1);
    GPHASE(3, 1, 1, 0);
    s_tile = subm10(s_tile + 4);
  }

  if (!FUSED) {
    #pragma unroll
    for (int mfg = 0; mfg < 8; ++mfg)
      #pragma unroll
      for (int nf = 0; nf < 4; ++nf)
        #pragma unroll
        for (int r = 0; r < 4; ++r) {
          int row = bm*256 + wm*128 + mfg*16 + qq*4 + r;
          int col = bnl*256 + nf*64 + wn*16 + c;
          outf[(size_t)row*2048 + col] = acc[mfg][nf][r];
        }
    return;
  }

  if (z <= 1) {
    // RoPE: pair (nf=2h, nf=2h+1) = (d, d+64) of head bnl*2+h, in-lane.
    u16* qk = (z == 0) ? outq : outk;
    const int d1 = wn*16 + c, d2 = d1 + 64;
    #pragma unroll
    for (int mfg = 0; mfg < 8; ++mfg)
      #pragma unroll
      for (int r = 0; r < 4; ++r) {
        int m  = bm*256 + wm*128 + mfg*16 + qq*4 + r;
        int bb = m >> 11, s = m & 2047;
        const float* cs = cosp + s*128;
        const float* sn = sinp + s*128;
        #pragma unroll
        for (int h = 0; h < 2; ++h) {
          u16* orow = qk + ((size_t)(bb*16 + bnl*2 + h)*2048 + s)*128;
          float v1 = acc[mfg][2*h][r], v2 = acc[mfg][2*h+1][r];
          orow[d1] = f2bf(v1*cs[d1] - v2*sn[d1]);
          orow[d2] = f2bf(v2*cs[d2] + v1*sn[d2]);
        }
      }
  } else {
    // V: transpose 256x256 tile via LDS (rows padded to 264), store [b,h,d,s].
    __syncthreads();
    #pragma unroll
    for (int mfg = 0; mfg < 8; ++mfg)
      #pragma unroll
      for (int nf = 0; nf < 4; ++nf)
        #pragma unroll
        for (int r = 0; r < 4; ++r) {
          int cl = nf*64 + wn*16 + c;               // output n within tile
          int rl = wm*128 + mfg*16 + qq*4 + r;      // s within tile
          lds[cl*264 + rl] = f2bf(acc[mfg][nf][r]);
        }
    __syncthreads();
    const int cl = t >> 1, half = (t & 1) * 128;
    const int bb = bm >> 3, s0 = (bm & 7) * 256;
    const int head = bnl*2 + (cl >> 7), d = cl & 127;
    u16* og = outv + ((size_t)(bb*16 + head)*128 + d)*2048 + s0 + half;
    #pragma unroll
    for (int j = 0; j < 16; ++j)
      *(u16x8*)&og[j*8] = *(const u16x8*)&lds[cl*264 + half + j*8];
  }
}

// ---------------------------------------------------------------------------
// Flash attention, causal, PAIRED q-tiles (validated round 4/6: 104 us).
// ---------------------------------------------------------------------------
__global__ __launch_bounds__(256, 2)
void attn_fwd(const u16* __restrict__ qw, const u16* __restrict__ kw,
              const u16* __restrict__ vw, u16* __restrict__ ow)
{
  __shared__ __attribute__((aligned(16))) u16 Klds[2][64*128];
  __shared__ __attribute__((aligned(16))) u16 Vlds[2][128*64];
  __shared__ __attribute__((aligned(16))) u16 Plds[4][16*72];

  const int t = threadIdx.x, lane = t & 63, w = t >> 6;
  const int c = lane & 15, qq = lane >> 4;
  const int ip = blockIdx.x, h = blockIdx.y, b = blockIdx.z;
  const int qlo = ip, qhi = 31 - ip;

  const size_t bh = (size_t)b*16 + h;
  const u16* Qg = qw + bh*(2048*128);
  const u16* Kg = kw + bh*(2048*128);
  const u16* Vg = vw + bh*(128*2048);
  u16* pw = &Plds[w][0];

  bf16x8 qf_hi[4], qf_lo[4];
  {
    const u16* qh = Qg + (size_t)(qhi*64 + w*16 + c)*128;
    const u16* ql = Qg + (size_t)(qlo*64 + w*16 + c)*128;
    #pragma unroll
    for (int ds = 0; ds < 4; ++ds) {
      qf_hi[ds] = *(const bf16x8*)(qh + ds*32 + qq*8);
      qf_lo[ds] = *(const bf16x8*)(ql + ds*32 + qq*8);
    }
  }

  float m_hi[4] = {-1e30f,-1e30f,-1e30f,-1e30f};
  float l_hi[4] = {0.f,0.f,0.f,0.f};
  f32x4 o_hi[8] = {};
  float m_lo[4] = {-1e30f,-1e30f,-1e30f,-1e30f};
  float l_lo[4] = {0.f,0.f,0.f,0.f};
  f32x4 o_lo[8] = {};

#define ASTAGE(BUF, KT) do {                                                  \
    const u16* kbase = Kg + (size_t)(KT)*8192;                                \
    _Pragma("unroll")                                                         \
    for (int it = 0; it < 4; ++it) {                                          \
      const u32 p  = it*256 + t;                                              \
      const u32 gl = p ^ ((p >> 4) & 7u);                                     \
      GLOAD16(kbase + gl*8, &Klds[BUF][p*8]);                                 \
    }                                                                         \
    _Pragma("unroll")                                                         \
    for (int it = 0; it < 4; ++it) {                                          \
      const u32 p  = it*256 + t;                                              \
      const u32 gl = p ^ ((p >> 3) & 7u);                                     \
      GLOAD16(Vg + (size_t)(gl >> 3)*2048 + (KT)*64 + (gl & 7u)*8,            \
              &Vlds[BUF][p*8]);                                               \
    }                                                                         \
  } while (0)

#define APROCESS(QF, OACC, MR, LR, QBASE, DIAG, BUF) do {                     \
    f32x4 sc[4] = {};                                                         \
    __builtin_amdgcn_s_setprio(1);                                            \
    _Pragma("unroll")                                                         \
    for (int ds = 0; ds < 4; ++ds) {                                          \
      _Pragma("unroll")                                                       \
      for (int nj = 0; nj < 4; ++nj) {                                        \
        const u32 row = nj*16 + c;                                            \
        const u32 p = (row*128 + ds*32 + qq*8) ^ ((row & 7u) << 3);           \
        bf16x8 kb = *(const bf16x8*)&Klds[BUF][p];                            \
        sc[nj] = MFMA16(QF[ds], kb, sc[nj]);                                  \
      }                                                                       \
    }                                                                         \
    __builtin_amdgcn_s_setprio(0);                                            \
    const int qg0 = (QBASE) + w*16 + qq*4;                                    \
    float escale[4];                                                          \
    _Pragma("unroll")                                                         \
    for (int r = 0; r < 4; ++r) {                                             \
      float mx = -1e30f;                                                      \
      _Pragma("unroll")                                                       \
      for (int nj = 0; nj < 4; ++nj) {                                        \
        float s = sc[nj][r] * ATT_SCALE;                                      \
        if ((DIAG) && (kt*64 + nj*16 + c) > (qg0 + r)) s = -1e30f;            \
        sc[nj][r] = s;                                                        \
        mx = fmaxf(mx, s);                                                    \
      }                                                                       \
      mx = fmaxf(mx, __shfl_xor(mx, 1));                                      \
      mx = fmaxf(mx, __shfl_xor(mx, 2));                                      \
      mx = fmaxf(mx, __shfl_xor(mx, 4));                                      \
      mx = fmaxf(mx, __shfl_xor(mx, 8));                                      \
      float mnew = fmaxf(MR[r], mx);                                          \
      escale[r] = __expf(MR[r] - mnew);                                       \
      MR[r] = mnew;                                                           \
      float sum = 0.f;                                                        \
      _Pragma("unroll")                                                       \
      for (int nj = 0; nj < 4; ++nj) {                                        \
        float pv = __expf(sc[nj][r] - mnew);                                  \
        sum += pv;                                                            \
        pw[(qq*4 + r)*72 + nj*16 + c] = f2bf(pv);                             \
      }                                                                       \
      sum += __shfl_xor(sum, 1);                                              \
      sum += __shfl_xor(sum, 2);                                              \
      sum += __shfl_xor(sum, 4);                                              \
      sum += __shfl_xor(sum, 8);                                              \
      LR[r] = LR[r]*escale[r] + sum;                                          \
    }                                                                         \
    _Pragma("unroll")                                                         \
    for (int nj8 = 0; nj8 < 8; ++nj8)                                         \
      _Pragma("unroll")                                                       \
      for (int r = 0; r < 4; ++r)                                             \
        OACC[nj8][r] *= escale[r];                                            \
    __builtin_amdgcn_s_setprio(1);                                            \
    _Pragma("unroll")                                                         \
    for (int ks = 0; ks < 2; ++ks) {                                          \
      bf16x8 pa = *(const bf16x8*)&pw[c*72 + ks*32 + qq*8];                   \
      _Pragma("unroll")                                                       \
      for (int nj8 = 0; nj8 < 8; ++nj8) {                                     \
        const u32 row = nj8*16 + c;                                           \
        const u32 p = (row*64 + ks*32 + qq*8) ^ ((row & 7u) << 3);            \
        bf16x8 vb = *(const bf16x8*)&Vlds[BUF][p];                            \
        OACC[nj8] = MFMA16(pa, vb, OACC[nj8]);                                \
      }                                                                       \
    }                                                                         \
    __builtin_amdgcn_s_setprio(0);                                            \
  } while (0)

  ASTAGE(0, 0);
  for (int kt = 0; kt <= qhi; ++kt) {
    const int cur = kt & 1;
    __syncthreads();
    if (kt < qhi) ASTAGE(cur ^ 1, kt + 1);
    APROCESS(qf_hi, o_hi, m_hi, l_hi, qhi*64, (kt == qhi), cur);
    if (kt <= qlo)
      APROCESS(qf_lo, o_lo, m_lo, l_lo, qlo*64, (kt == qlo), cur);
  }

#undef ASTAGE
#undef APROCESS

  {
    float inv[4];
    #pragma unroll
    for (int r = 0; r < 4; ++r) inv[r] = 1.0f / l_hi[r];
    u16* og = ow + ((size_t)b*2048 + qhi*64 + w*16)*2048 + h*128;
    #pragma unroll
    for (int nj8 = 0; nj8 < 8; ++nj8)
      #pragma unroll
      for (int r = 0; r < 4; ++r)
        og[(size_t)(qq*4 + r)*2048 + nj8*16 + c] = f2bf(o_hi[nj8][r]*inv[r]);
  }
  {
    float inv[4];
    #pragma unroll
    for (int r = 0; r < 4; ++r) inv[r] = 1.0f / l_lo[r];
    u16* og = ow + ((size_t)b*2048 + qlo*64 + w*16)*2048 + h*128;
    #pragma unroll
    for (int nj8 = 0; nj8 < 8; ++nj8)
      #pragma unroll
      for (int r = 0; r < 4; ++r)
        og[(size_t)(qq*4 + r)*2048 + nj8*16 + c] = f2bf(o_lo[nj8][r]*inv[r]);
  }
}

extern "C" void kernel_launch(void* const* d_in, const int* in_sizes, int n_in,
                              void* d_out, int out_size, void* d_ws, size_t ws_size,
                              hipStream_t stream)
{
  const float* hs   = (const float*)d_in[0];
  const float* cosp = (const float*)d_in[1];
  const float* sinp = (const float*)d_in[2];
  const float* Wq   = (const float*)d_in[3];
  const float* Wk   = (const float*)d_in[4];
  const float* Wv   = (const float*)d_in[5];
  const float* Wo   = (const float*)d_in[6];

  u16* q_ws  = (u16*)d_ws;
  u16* k_ws  = q_ws  + 8388608;
  u16* vt_ws = k_ws  + 8388608;
  u16* ao_ws = vt_ws + 8388608;
  u16* hs_b  = ao_ws + 8388608;
  u16* wq_b  = hs_b  + 8388608;
  u16* wk_b  = wq_b  + 4194304;
  u16* wv_b  = wk_b  + 4194304;
  u16* wo_b  = wv_b  + 4194304;

  CvtArgs ca;
  ca.src[0]=hs; ca.src[1]=Wq; ca.src[2]=Wk; ca.src[3]=Wv; ca.src[4]=Wo;
  ca.dst[0]=hs_b; ca.dst[1]=wq_b; ca.dst[2]=wk_b; ca.dst[3]=wv_b; ca.dst[4]=wo_b;
  ca.nblk[0]=4096; ca.nblk[1]=2048; ca.nblk[2]=2048; ca.nblk[3]=2048; ca.nblk[4]=2048;

  cvt_bf16<<<dim3(4096, 5), dim3(256), 0, stream>>>(ca);

  gemm9<1><<<dim3(384), dim3(512), 0, stream>>>(
      hs_b, wq_b, wk_b, wv_b, q_ws, k_ws, vt_ws, nullptr, cosp, sinp);

  attn_fwd<<<dim3(16, 16, 2), dim3(256), 0, stream>>>(q_ws, k_ws, vt_ws, ao_ws);

  gemm9<0><<<dim3(128), dim3(512), 0, stream>>>(
      ao_ws, wo_b, nullptr, nullptr, nullptr, nullptr, nullptr,
      (float*)d_out, nullptr, nullptr);
}